// Round 2
// baseline (2031.178 us; speedup 1.0000x reference)
//
#include <hip/hip_runtime.h>
#include <hip/hip_bf16.h>
#include <stdint.h>

#define N_TOK 4096
#define DIM   2048
#define VOCAB 50257
#define VPAD  50304   // 393 * 128
#define IGNORE_IDX (-100)

typedef short  bf16x8 __attribute__((ext_vector_type(8)));
typedef float  f32x4  __attribute__((ext_vector_type(4)));
typedef unsigned short u16x8 __attribute__((ext_vector_type(8)));

typedef const __attribute__((address_space(1))) unsigned int* gptr_t;
typedef __attribute__((address_space(3))) unsigned int*       lptr_t;

__device__ __forceinline__ unsigned short f2bf(float f) {
  union { float f; uint32_t u; } c; c.f = f;
  uint32_t u = c.u;
  return (unsigned short)((u + 0x7FFFu + ((u >> 16) & 1u)) >> 16);
}

// ---- fp32 -> bf16 conversion: weight (padded to VPAD rows, pad=0) + input ----
__global__ void cvt_all(const float* __restrict__ w, const float* __restrict__ a,
                        unsigned short* __restrict__ wo, unsigned short* __restrict__ ao) {
  const long long t   = (long long)blockIdx.x * 256 + threadIdx.x;
  long long idx = t << 3;                    // 8 elements per thread
  if (idx < (long long)VPAD * DIM) {
    const long long v = idx >> 11;           // / DIM
    u16x8 r = {0, 0, 0, 0, 0, 0, 0, 0};
    if (v < VOCAB) {
      const float4* p = (const float4*)(w + idx);
      const float4 x0 = p[0];
      const float4 x1 = p[1];
      r[0] = f2bf(x0.x); r[1] = f2bf(x0.y); r[2] = f2bf(x0.z); r[3] = f2bf(x0.w);
      r[4] = f2bf(x1.x); r[5] = f2bf(x1.y); r[6] = f2bf(x1.z); r[7] = f2bf(x1.w);
    }
    *(u16x8*)(wo + idx) = r;
  } else {
    idx -= (long long)VPAD * DIM;
    const float4* p = (const float4*)(a + idx);
    const float4 x0 = p[0];
    const float4 x1 = p[1];
    u16x8 r;
    r[0] = f2bf(x0.x); r[1] = f2bf(x0.y); r[2] = f2bf(x0.z); r[3] = f2bf(x0.w);
    r[4] = f2bf(x1.x); r[5] = f2bf(x1.y); r[6] = f2bf(x1.z); r[7] = f2bf(x1.w);
    *(u16x8*)(ao + idx) = r;
  }
}

// ---- fused GEMM + online partial-sumexp + target-logit capture ----
// C[m, v] = sum_k input[m,k] * weight[v,k]   (both K-contiguous -> NT GEMM)
// 128x128 tile, BK=32, 4 waves (2x2), 4x4 frags of 16x16x32 bf16 MFMA.
// Double-buffered LDS with one-iteration prefetch; XOR bank swizzle:
//   logical (row r, 16B chunk c) lives at physical slot r*4 + (c ^ ((r>>1)&3)).
__global__ __launch_bounds__(256) void flce_gemm(
    const unsigned short* __restrict__ A,   // [N_TOK][DIM]  bf16
    const unsigned short* __restrict__ B,   // [VPAD][DIM]   bf16
    const float* __restrict__ bias,         // [VOCAB]
    const int* __restrict__ target,         // [N_TOK]
    float* __restrict__ sumexp,             // [N_TOK] (pre-zeroed)
    float* __restrict__ tgtlog)             // [N_TOK]
{
  __shared__ unsigned short As[2][128 * 32];   // 2 x 8 KB
  __shared__ unsigned short Bs[2][128 * 32];   // 2 x 8 KB
  __shared__ int tgt_s[128];

  const int tid  = threadIdx.x;
  const int lane = tid & 63;
  const int wave = tid >> 6;
  const int wm   = wave >> 1;               // wave row (0..1) -> 64 rows
  const int wn   = wave & 1;                // wave col (0..1) -> 64 cols
  const int m0   = blockIdx.x * 128;
  const int v0   = blockIdx.y * 128;

  if (tid < 128) tgt_s[tid] = target[m0 + tid];

  // Staging: 512 x 16B physical slots per matrix; thread t writes slots t, t+256
  // (contiguous: wave-uniform base + lane*16).  Slot s holds logical
  // (row = s>>2, chunk = (s&3) ^ ((s>>3)&3)).
  const int r0  = tid >> 2;
  const int c0s = ((tid & 3) ^ ((tid >> 3) & 3)) * 8;   // swizzled k-chunk
  const unsigned short* ag0 = A + (m0 + r0)      * DIM + c0s;
  const unsigned short* ag1 = A + (m0 + 64 + r0) * DIM + c0s;
  const unsigned short* bg0 = B + (v0 + r0)      * DIM + c0s;
  const unsigned short* bg1 = B + (v0 + 64 + r0) * DIM + c0s;

  f32x4 acc[4][4];
#pragma unroll
  for (int i = 0; i < 4; i++)
#pragma unroll
    for (int j = 0; j < 4; j++) acc[i][j] = (f32x4){0.f, 0.f, 0.f, 0.f};

  const int mrow = lane & 15;               // row/col within 16x16 frag
  const int quad = lane >> 4;               // k-group for A/B, row-group for C
  const int swz  = quad ^ ((mrow >> 1) & 3);// swizzled chunk for frag reads

#define STAGE(bufi, kt) do {                                                             \
    unsigned short* a_ = As[bufi]; unsigned short* b_ = Bs[bufi];                        \
    __builtin_amdgcn_global_load_lds((gptr_t)(const void*)(ag0 + (kt)),                  \
                                     (lptr_t)(void*)(a_ + tid * 8),         16, 0, 0);   \
    __builtin_amdgcn_global_load_lds((gptr_t)(const void*)(ag1 + (kt)),                  \
                                     (lptr_t)(void*)(a_ + (tid + 256) * 8), 16, 0, 0);   \
    __builtin_amdgcn_global_load_lds((gptr_t)(const void*)(bg0 + (kt)),                  \
                                     (lptr_t)(void*)(b_ + tid * 8),         16, 0, 0);   \
    __builtin_amdgcn_global_load_lds((gptr_t)(const void*)(bg1 + (kt)),                  \
                                     (lptr_t)(void*)(b_ + (tid + 256) * 8), 16, 0, 0);   \
  } while (0)

  STAGE(0, 0);                               // prologue: tile 0 -> buffer 0

  const int NK = DIM / 32;                   // 64 K-iterations
  for (int t = 0; t < NK; t++) {
    // Drains the loads for tile t (issued last iter / prologue) AND guarantees
    // everyone is done reading the buffer tile t+1 will overwrite.
    __syncthreads();
    if (t + 1 < NK) STAGE((t + 1) & 1, (t + 1) * 32);

    const unsigned short* a_ = As[t & 1];
    const unsigned short* b_ = Bs[t & 1];
    bf16x8 av[4], bv[4];
#pragma unroll
    for (int f = 0; f < 4; f++)
      av[f] = *(const bf16x8*)(a_ + ((wm * 64 + f * 16 + mrow) * 4 + swz) * 8);
#pragma unroll
    for (int f = 0; f < 4; f++)
      bv[f] = *(const bf16x8*)(b_ + ((wn * 64 + f * 16 + mrow) * 4 + swz) * 8);

#pragma unroll
    for (int i = 0; i < 4; i++)
#pragma unroll
      for (int j = 0; j < 4; j++)
        acc[i][j] = __builtin_amdgcn_mfma_f32_16x16x32_bf16(av[i], bv[j], acc[i][j], 0, 0, 0);
  }
#undef STAGE

  // ---- epilogue: bias add, exp, per-row partial sums, target logit ----
  // C/D layout (verified m89): col = lane&15, row = (lane>>4)*4 + reg
  const int colb = v0 + wn * 64;
#pragma unroll
  for (int i = 0; i < 4; i++) {
    const int rowl = wm * 64 + i * 16 + quad * 4;   // local row base (reg adds 0..3)
    float rs[4] = {0.f, 0.f, 0.f, 0.f};
#pragma unroll
    for (int j = 0; j < 4; j++) {
      const int colg = colb + j * 16 + mrow;
      if (colg < VOCAB) {
        const float bvv = bias[colg];
#pragma unroll
        for (int r = 0; r < 4; r++) {
          const float lg = acc[i][j][r] + bvv;
          rs[r] += __expf(lg);
          if (tgt_s[rowl + r] == colg) tgtlog[m0 + rowl + r] = lg;
        }
      }
    }
#pragma unroll
    for (int r = 0; r < 4; r++) {
      float v = rs[r];
      v += __shfl_xor(v, 1);
      v += __shfl_xor(v, 2);
      v += __shfl_xor(v, 4);
      v += __shfl_xor(v, 8);
      if (mrow == 0) atomicAdd(&sumexp[m0 + rowl + r], v);
    }
  }
}

// ---- final scalar reduction: loss and z_loss ----
__global__ void flce_final(const float* __restrict__ sumexp,
                           const float* __restrict__ tgtlog,
                           const int* __restrict__ target,
                           float* __restrict__ out) {
  const int tid = threadIdx.x;
  float ls = 0.f, zs = 0.f;
  int cnt = 0;
  for (int r = tid; r < N_TOK; r += 256) {
    const int t = target[r];
    if (t != IGNORE_IDX) {
      const float lse = logf(sumexp[r]);
      const float z = 1e-4f * lse * lse;
      ls += (lse - tgtlog[r]) + z;
      zs += z;
      cnt++;
    }
  }
#pragma unroll
  for (int off = 32; off > 0; off >>= 1) {
    ls += __shfl_down(ls, off);
    zs += __shfl_down(zs, off);
    cnt += __shfl_down(cnt, off);
  }
  __shared__ float sls[4], szs[4];
  __shared__ int scnt[4];
  const int lane = tid & 63, wv = tid >> 6;
  if (lane == 0) { sls[wv] = ls; szs[wv] = zs; scnt[wv] = cnt; }
  __syncthreads();
  if (tid == 0) {
    float L = 0.f, Z = 0.f;
    int C = 0;
    for (int w = 0; w < 4; w++) { L += sls[w]; Z += szs[w]; C += scnt[w]; }
    const float n = (float)(C > 0 ? C : 1);
    out[0] = L / n;
    out[1] = Z / n;
  }
}

extern "C" void kernel_launch(void* const* d_in, const int* in_sizes, int n_in,
                              void* d_out, int out_size, void* d_ws, size_t ws_size,
                              hipStream_t stream) {
  const float* input  = (const float*)d_in[0];
  const float* weight = (const float*)d_in[1];
  const float* bias   = (const float*)d_in[2];
  const int*   target = (const int*)d_in[3];
  float* out = (float*)d_out;

  unsigned short* wbf = (unsigned short*)d_ws;               // VPAD*DIM bf16
  unsigned short* abf = wbf + (size_t)VPAD * DIM;            // N_TOK*DIM bf16
  float* sumexp = (float*)(abf + (size_t)N_TOK * DIM);       // N_TOK f32
  float* tgtlog = sumexp + N_TOK;                            // N_TOK f32

  hipMemsetAsync(sumexp, 0, N_TOK * sizeof(float), stream);
  cvt_all<<<((VPAD + N_TOK) * (long long)DIM) / 2048, 256, 0, stream>>>(weight, input, wbf, abf);
  flce_gemm<<<dim3(N_TOK / 128, VPAD / 128), 256, 0, stream>>>(abf, wbf, bias, target, sumexp, tgtlog);
  flce_final<<<1, 256, 0, stream>>>(sumexp, tgtlog, target, out);
}

// Round 3
// 1739.897 us; speedup vs baseline: 1.1674x; 1.1674x over previous
//
#include <hip/hip_runtime.h>
#include <hip/hip_bf16.h>
#include <stdint.h>

#define N_TOK 4096
#define DIM   2048
#define VOCAB 50257
#define VPAD  50304   // 393 * 128
#define IGNORE_IDX (-100)

typedef short  bf16x8 __attribute__((ext_vector_type(8)));
typedef float  f32x4  __attribute__((ext_vector_type(4)));
typedef unsigned short u16x8 __attribute__((ext_vector_type(8)));

typedef const __attribute__((address_space(1))) unsigned int* gptr_t;
typedef __attribute__((address_space(3))) unsigned int*       lptr_t;

__device__ __forceinline__ unsigned short f2bf(float f) {
  union { float f; uint32_t u; } c; c.f = f;
  uint32_t u = c.u;
  return (unsigned short)((u + 0x7FFFu + ((u >> 16) & 1u)) >> 16);
}

// ---- fp32 -> bf16 conversion: weight (padded to VPAD rows, pad=0) + input ----
__global__ void cvt_all(const float* __restrict__ w, const float* __restrict__ a,
                        unsigned short* __restrict__ wo, unsigned short* __restrict__ ao) {
  const long long t   = (long long)blockIdx.x * 256 + threadIdx.x;
  long long idx = t << 3;                    // 8 elements per thread
  if (idx < (long long)VPAD * DIM) {
    const long long v = idx >> 11;           // / DIM
    u16x8 r = {0, 0, 0, 0, 0, 0, 0, 0};
    if (v < VOCAB) {
      const float4* p = (const float4*)(w + idx);
      const float4 x0 = p[0];
      const float4 x1 = p[1];
      r[0] = f2bf(x0.x); r[1] = f2bf(x0.y); r[2] = f2bf(x0.z); r[3] = f2bf(x0.w);
      r[4] = f2bf(x1.x); r[5] = f2bf(x1.y); r[6] = f2bf(x1.z); r[7] = f2bf(x1.w);
    }
    *(u16x8*)(wo + idx) = r;
  } else {
    idx -= (long long)VPAD * DIM;
    const float4* p = (const float4*)(a + idx);
    const float4 x0 = p[0];
    const float4 x1 = p[1];
    u16x8 r;
    r[0] = f2bf(x0.x); r[1] = f2bf(x0.y); r[2] = f2bf(x0.z); r[3] = f2bf(x0.w);
    r[4] = f2bf(x1.x); r[5] = f2bf(x1.y); r[6] = f2bf(x1.z); r[7] = f2bf(x1.w);
    *(u16x8*)(ao + idx) = r;
  }
}

// ---- fused GEMM + online partial-sumexp + target-logit capture ----
// C[m, v] = sum_k input[m,k] * weight[v,k]   (both K-contiguous -> NT GEMM)
// 128x128 tile, BK=64, single-buffer LDS, 4 waves (2x2), 4x4 frags of
// 16x16x32 bf16 MFMA, 2 k-steps per staged tile (32 MFMA per drain).
// XOR bank swizzle: logical (row r, 16B chunk c) at physical slot
// r*8 + (c ^ (r&7))  -> staging keeps each row's 128B window (coalesced),
// reads spread all 8 bank groups (2-way aliasing only = free).
__global__ __launch_bounds__(256) void flce_gemm(
    const unsigned short* __restrict__ A,   // [N_TOK][DIM]  bf16
    const unsigned short* __restrict__ B,   // [VPAD][DIM]   bf16
    const float* __restrict__ bias,         // [VOCAB]
    const int* __restrict__ target,         // [N_TOK]
    float* __restrict__ sumexp,             // [N_TOK] (pre-zeroed)
    float* __restrict__ tgtlog)             // [N_TOK]
{
  __shared__ unsigned short As[128 * 64];   // 16 KB
  __shared__ unsigned short Bs[128 * 64];   // 16 KB
  __shared__ int tgt_s[128];

  const int tid  = threadIdx.x;
  const int lane = tid & 63;
  const int wave = tid >> 6;
  const int wm   = wave >> 1;               // wave row (0..1) -> 64 rows
  const int wn   = wave & 1;                // wave col (0..1) -> 64 cols
  const int m0   = blockIdx.x * 128;
  const int v0   = blockIdx.y * 128;

  if (tid < 128) tgt_s[tid] = target[m0 + tid];

  // Staging: 1024 x 16B slots per matrix; thread t writes slots t, t+256,
  // t+512, t+768 (each wave's 64 lanes contiguous -> valid global_load_lds).
  // Slot s: row = s>>3 (rows step by 32 across the 4 slots -> r&7 invariant),
  // physical chunk = s&7, logical chunk = (s&7) ^ (r&7).
  const int r0 = tid >> 3;                                   // 0..31
  const int c0 = (((tid & 7) ^ (r0 & 7))) * 8;               // logical k-offset
  const unsigned short* ag0 = A + (m0 + r0)      * DIM + c0;
  const unsigned short* ag1 = A + (m0 + 32 + r0) * DIM + c0;
  const unsigned short* ag2 = A + (m0 + 64 + r0) * DIM + c0;
  const unsigned short* ag3 = A + (m0 + 96 + r0) * DIM + c0;
  const unsigned short* bg0 = B + (v0 + r0)      * DIM + c0;
  const unsigned short* bg1 = B + (v0 + 32 + r0) * DIM + c0;
  const unsigned short* bg2 = B + (v0 + 64 + r0) * DIM + c0;
  const unsigned short* bg3 = B + (v0 + 96 + r0) * DIM + c0;

  f32x4 acc[4][4];
#pragma unroll
  for (int i = 0; i < 4; i++)
#pragma unroll
    for (int j = 0; j < 4; j++) acc[i][j] = (f32x4){0.f, 0.f, 0.f, 0.f};

  const int mrow = lane & 15;               // row/col within 16x16 frag
  const int quad = lane >> 4;               // k-quad for A/B, row-group for C

  for (int kt = 0; kt < DIM; kt += 64) {
    __syncthreads();   // all ds_reads of previous tile done before overwrite
    __builtin_amdgcn_global_load_lds((gptr_t)(const void*)(ag0 + kt), (lptr_t)(void*)(As + tid * 8),         16, 0, 0);
    __builtin_amdgcn_global_load_lds((gptr_t)(const void*)(ag1 + kt), (lptr_t)(void*)(As + (tid + 256) * 8), 16, 0, 0);
    __builtin_amdgcn_global_load_lds((gptr_t)(const void*)(ag2 + kt), (lptr_t)(void*)(As + (tid + 512) * 8), 16, 0, 0);
    __builtin_amdgcn_global_load_lds((gptr_t)(const void*)(ag3 + kt), (lptr_t)(void*)(As + (tid + 768) * 8), 16, 0, 0);
    __builtin_amdgcn_global_load_lds((gptr_t)(const void*)(bg0 + kt), (lptr_t)(void*)(Bs + tid * 8),         16, 0, 0);
    __builtin_amdgcn_global_load_lds((gptr_t)(const void*)(bg1 + kt), (lptr_t)(void*)(Bs + (tid + 256) * 8), 16, 0, 0);
    __builtin_amdgcn_global_load_lds((gptr_t)(const void*)(bg2 + kt), (lptr_t)(void*)(Bs + (tid + 512) * 8), 16, 0, 0);
    __builtin_amdgcn_global_load_lds((gptr_t)(const void*)(bg3 + kt), (lptr_t)(void*)(Bs + (tid + 768) * 8), 16, 0, 0);
    __syncthreads();   // drains vmcnt(0): staged tile visible

#pragma unroll
    for (int h = 0; h < 2; h++) {           // two K=32 steps per staged tile
      bf16x8 av[4], bv[4];
#pragma unroll
      for (int f = 0; f < 4; f++) {
        const int row = wm * 64 + f * 16 + mrow;
        const int phys = (h * 4 + quad) ^ (row & 7);
        av[f] = *(const bf16x8*)(As + (row * 8 + phys) * 8);
      }
#pragma unroll
      for (int f = 0; f < 4; f++) {
        const int row = wn * 64 + f * 16 + mrow;
        const int phys = (h * 4 + quad) ^ (row & 7);
        bv[f] = *(const bf16x8*)(Bs + (row * 8 + phys) * 8);
      }
#pragma unroll
      for (int i = 0; i < 4; i++)
#pragma unroll
        for (int j = 0; j < 4; j++)
          acc[i][j] = __builtin_amdgcn_mfma_f32_16x16x32_bf16(av[i], bv[j], acc[i][j], 0, 0, 0);
    }
  }

  // ---- epilogue: bias add, exp, per-row partial sums, target logit ----
  // C/D layout (verified m89): col = lane&15, row = (lane>>4)*4 + reg
  const int colb = v0 + wn * 64;
#pragma unroll
  for (int i = 0; i < 4; i++) {
    const int rowl = wm * 64 + i * 16 + quad * 4;   // local row base (reg adds 0..3)
    float rs[4] = {0.f, 0.f, 0.f, 0.f};
#pragma unroll
    for (int j = 0; j < 4; j++) {
      const int colg = colb + j * 16 + mrow;
      if (colg < VOCAB) {
        const float bvv = bias[colg];
#pragma unroll
        for (int r = 0; r < 4; r++) {
          const float lg = acc[i][j][r] + bvv;
          rs[r] += __expf(lg);
          if (tgt_s[rowl + r] == colg) tgtlog[m0 + rowl + r] = lg;
        }
      }
    }
#pragma unroll
    for (int r = 0; r < 4; r++) {
      float v = rs[r];
      v += __shfl_xor(v, 1);
      v += __shfl_xor(v, 2);
      v += __shfl_xor(v, 4);
      v += __shfl_xor(v, 8);
      if (mrow == 0) atomicAdd(&sumexp[m0 + rowl + r], v);
    }
  }
}

// ---- final scalar reduction: loss and z_loss ----
__global__ void flce_final(const float* __restrict__ sumexp,
                           const float* __restrict__ tgtlog,
                           const int* __restrict__ target,
                           float* __restrict__ out) {
  const int tid = threadIdx.x;
  float ls = 0.f, zs = 0.f;
  int cnt = 0;
  for (int r = tid; r < N_TOK; r += 256) {
    const int t = target[r];
    if (t != IGNORE_IDX) {
      const float lse = logf(sumexp[r]);
      const float z = 1e-4f * lse * lse;
      ls += (lse - tgtlog[r]) + z;
      zs += z;
      cnt++;
    }
  }
#pragma unroll
  for (int off = 32; off > 0; off >>= 1) {
    ls += __shfl_down(ls, off);
    zs += __shfl_down(zs, off);
    cnt += __shfl_down(cnt, off);
  }
  __shared__ float sls[4], szs[4];
  __shared__ int scnt[4];
  const int lane = tid & 63, wv = tid >> 6;
  if (lane == 0) { sls[wv] = ls; szs[wv] = zs; scnt[wv] = cnt; }
  __syncthreads();
  if (tid == 0) {
    float L = 0.f, Z = 0.f;
    int C = 0;
    for (int w = 0; w < 4; w++) { L += sls[w]; Z += szs[w]; C += scnt[w]; }
    const float n = (float)(C > 0 ? C : 1);
    out[0] = L / n;
    out[1] = Z / n;
  }
}

extern "C" void kernel_launch(void* const* d_in, const int* in_sizes, int n_in,
                              void* d_out, int out_size, void* d_ws, size_t ws_size,
                              hipStream_t stream) {
  const float* input  = (const float*)d_in[0];
  const float* weight = (const float*)d_in[1];
  const float* bias   = (const float*)d_in[2];
  const int*   target = (const int*)d_in[3];
  float* out = (float*)d_out;

  unsigned short* wbf = (unsigned short*)d_ws;               // VPAD*DIM bf16
  unsigned short* abf = wbf + (size_t)VPAD * DIM;            // N_TOK*DIM bf16
  float* sumexp = (float*)(abf + (size_t)N_TOK * DIM);       // N_TOK f32
  float* tgtlog = sumexp + N_TOK;                            // N_TOK f32

  hipMemsetAsync(sumexp, 0, N_TOK * sizeof(float), stream);
  cvt_all<<<((VPAD + N_TOK) * (long long)DIM) / 2048, 256, 0, stream>>>(weight, input, wbf, abf);
  flce_gemm<<<dim3(N_TOK / 128, VPAD / 128), 256, 0, stream>>>(abf, wbf, bias, target, sumexp, tgtlog);
  flce_final<<<1, 256, 0, stream>>>(sumexp, tgtlog, target, out);
}